// Round 3
// baseline (266.389 us; speedup 1.0000x reference)
//
#include <hip/hip_runtime.h>
#include <math.h>

#define DMODEL 1024
#define SEQ 2048
#define BATCH 4
#define SCALE_INV (1.0f/32.0f)   // 1/sqrt(1024)

typedef unsigned short ushort_t;
typedef __attribute__((ext_vector_type(8))) short bf16x8;   // 8 bf16 in 4 VGPRs
typedef __attribute__((ext_vector_type(4))) float f32x4;

// fp32 -> bf16, round-to-nearest-even
__device__ __forceinline__ ushort_t f2bf(float f) {
    unsigned int u = __float_as_uint(f);
    unsigned int rounding = 0x7FFFu + ((u >> 16) & 1u);
    return (ushort_t)((u + rounding) >> 16);
}

#define GLOAD16(SRC, DST) \
    __builtin_amdgcn_global_load_lds( \
        (const __attribute__((address_space(1))) void*)(SRC), \
        (__attribute__((address_space(3))) void*)(DST), 16, 0, 0)

// bijective XCD swizzle (nwg % 8 == 0): consecutive remapped ids stay on one XCD
__device__ __forceinline__ int xcd_swz(int bid, int nwg) {
    return (bid & 7) * (nwg >> 3) + (bid >> 3);
}

// ---------------------------------------------------------------------------
// Shared MFMA GEMM core: C(128x128) += A(128xK) * Bt(128xK)^T
// A row-major MxK (lda), Bt row-major NxK (ldb), both K-contiguous.
// 256 threads = 4 waves (2x2), each wave owns 64x64 = 4x4 16x16x32 fragments.
// LDS layout is FRAGMENT-ORDERED: 8 subtiles of 16 rows x 32 k per operand;
// subtile `sub`, slot l holds (row = sub*16 + (l&15), k = (l>>4)*8 .. +7).
// global_load_lds dest is linear (base + lane*16); the per-lane GLOBAL source
// is permuted to match (rule #21). Fragment ds_read_b128 is then a fully
// contiguous 1 KB per wave -> zero bank conflicts.
// ---------------------------------------------------------------------------
__device__ __forceinline__ void gemm_core_128(
    const ushort_t* __restrict__ A, int lda,
    const ushort_t* __restrict__ Bt, int ldb,
    int arow0, int brow0, int ksteps,
    ushort_t* As, ushort_t* Bs,
    f32x4 acc[4][4])
{
    const int tid = threadIdx.x;
    const int l   = tid & 63;
    const int w   = tid >> 6;      // wave 0..3
    const int wr  = w >> 1;        // wave row (0..1)
    const int wc  = w & 1;         // wave col (0..1)
    const int fr  = l & 15;        // fragment row within subtile
    const int kg  = l >> 4;        // k-group (8 bf16 each)

    for (int s = 0; s < ksteps; ++s) {
        const int k0 = s * 32;
        // stage A: wave w fills subtiles 2w, 2w+1 (rows 32w .. 32w+31)
        #pragma unroll
        for (int i = 0; i < 2; ++i) {
            const int sub = w * 2 + i;
            GLOAD16(A + (size_t)(arow0 + sub * 16 + fr) * lda + k0 + kg * 8,
                    (char*)As + sub * 1024);
        }
        // stage B
        #pragma unroll
        for (int i = 0; i < 2; ++i) {
            const int sub = w * 2 + i;
            GLOAD16(Bt + (size_t)(brow0 + sub * 16 + fr) * ldb + k0 + kg * 8,
                    (char*)Bs + sub * 1024);
        }
        __syncthreads();   // drains vmcnt(0) then barrier

        bf16x8 a[4], b[4];
        #pragma unroll
        for (int m = 0; m < 4; ++m)
            a[m] = *(const bf16x8*)(As + (wr * 4 + m) * 512 + l * 8);
        #pragma unroll
        for (int n = 0; n < 4; ++n)
            b[n] = *(const bf16x8*)(Bs + (wc * 4 + n) * 512 + l * 8);
        #pragma unroll
        for (int m = 0; m < 4; ++m)
            #pragma unroll
            for (int n = 0; n < 4; ++n)
                acc[m][n] = __builtin_amdgcn_mfma_f32_16x16x32_bf16(a[m], b[n], acc[m][n], 0, 0, 0);
        __syncthreads();   // protect LDS before next staging
    }
}

// ---------------------------------------------------------------------------
// QKV projection: out = x @ W + b  (W^T pre-transposed to N x K bf16).
// 1D grid (1536 blocks), XCD-swizzled; z = Q (scaled) / K / V.
// ---------------------------------------------------------------------------
__global__ __launch_bounds__(256) void qkv_gemm_mfma(
    const ushort_t* __restrict__ x,
    const ushort_t* __restrict__ wtq, const ushort_t* __restrict__ wtk, const ushort_t* __restrict__ wtv,
    const float* __restrict__ bq, const float* __restrict__ bk, const float* __restrict__ bv,
    ushort_t* __restrict__ q, ushort_t* __restrict__ k, ushort_t* __restrict__ v)
{
    __shared__ __align__(16) ushort_t As[128 * 32];
    __shared__ __align__(16) ushort_t Bs[128 * 32];

    const int wg = xcd_swz(blockIdx.x, 8 * 64 * 3);
    const int z  = wg >> 9;           // 512 blocks per matrix
    const int r  = wg & 511;
    const int by = r >> 3;            // row tile (64)
    const int bx = r & 7;             // col tile (8) -- fastest: shares A-panel

    const ushort_t* Bt; const float* bias; ushort_t* out; float scale;
    if (z == 0)      { Bt = wtq; bias = bq; out = q; scale = SCALE_INV; }
    else if (z == 1) { Bt = wtk; bias = bk; out = k; scale = 1.0f; }
    else             { Bt = wtv; bias = bv; out = v; scale = 1.0f; }

    const int arow0 = by * 128;
    const int brow0 = bx * 128;

    f32x4 acc[4][4];
    #pragma unroll
    for (int m = 0; m < 4; ++m)
        #pragma unroll
        for (int n = 0; n < 4; ++n)
            acc[m][n] = (f32x4)(0.f);

    gemm_core_128(x, DMODEL, Bt, DMODEL, arow0, brow0, DMODEL / 32, As, Bs, acc);

    const int l  = threadIdx.x & 63;
    const int w  = threadIdx.x >> 6;
    const int wr = w >> 1, wc = w & 1;
    #pragma unroll
    for (int n = 0; n < 4; ++n) {
        const int gcol = brow0 + wc * 64 + n * 16 + (l & 15);
        const float bb = bias[gcol];
        #pragma unroll
        for (int m = 0; m < 4; ++m) {
            #pragma unroll
            for (int j = 0; j < 4; ++j) {
                const int grow = arow0 + wr * 64 + m * 16 + (l >> 4) * 4 + j;
                out[(size_t)grow * DMODEL + gcol] = f2bf((acc[m][n][j] + bb) * scale);
            }
        }
    }
}

// ---------------------------------------------------------------------------
// scores = Q K^T  (scale folded into Q). Triangular block skip. fp32 out.
// ---------------------------------------------------------------------------
__global__ __launch_bounds__(256) void qkt_gemm_mfma(
    const ushort_t* __restrict__ q, const ushort_t* __restrict__ k,
    float* __restrict__ scores)
{
    const int wg = xcd_swz(blockIdx.x, 16 * 16 * BATCH);
    const int b  = wg >> 8;
    const int r  = wg & 255;
    const int st = r >> 4;
    const int tt = r & 15;
    if (tt > st) return;         // fully masked block

    __shared__ __align__(16) ushort_t As[128 * 32];
    __shared__ __align__(16) ushort_t Bs[128 * 32];

    const ushort_t* A  = q + (size_t)b * SEQ * DMODEL;
    const ushort_t* Bt = k + (size_t)b * SEQ * DMODEL;
    float* out = scores + (size_t)b * SEQ * SEQ;

    f32x4 acc[4][4];
    #pragma unroll
    for (int m = 0; m < 4; ++m)
        #pragma unroll
        for (int n = 0; n < 4; ++n)
            acc[m][n] = (f32x4)(0.f);

    gemm_core_128(A, DMODEL, Bt, DMODEL, st * 128, tt * 128, DMODEL / 32, As, Bs, acc);

    const int l  = threadIdx.x & 63;
    const int w  = threadIdx.x >> 6;
    const int wr = w >> 1, wc = w & 1;
    #pragma unroll
    for (int m = 0; m < 4; ++m) {
        #pragma unroll
        for (int n = 0; n < 4; ++n) {
            const int gcol = tt * 128 + wc * 64 + n * 16 + (l & 15);
            #pragma unroll
            for (int j = 0; j < 4; ++j) {
                const int grow = st * 128 + wr * 64 + m * 16 + (l >> 4) * 4 + j;
                out[(size_t)grow * SEQ + gcol] = acc[m][n][j];
            }
        }
    }
}

// ---------------------------------------------------------------------------
// Row softmax over causal prefix; writes P (bf16) in place over the fp32 row.
// float4 loads, __expf, ushort4 stores; zero-fills to 128-tile boundary.
// ---------------------------------------------------------------------------
__global__ __launch_bounds__(256) void softmax_rows(float* __restrict__ scores)
{
    const int s = blockIdx.x;
    const int b = blockIdx.y;
    const int tid = threadIdx.x;

    float* row = scores + ((size_t)b * SEQ + s) * SEQ;
    ushort_t* prow = (ushort_t*)row;
    const int nt = s + 1;

    __shared__ float e_sh[SEQ];    // 8 KB
    __shared__ float red[256];

    float lmax = -INFINITY;
    const int nt4 = nt >> 2;
    for (int i = tid; i < nt4; i += 256) {
        const float4 f = ((const float4*)row)[i];
        ((float4*)e_sh)[i] = f;
        lmax = fmaxf(lmax, fmaxf(fmaxf(f.x, f.y), fmaxf(f.z, f.w)));
    }
    for (int t = nt4 * 4 + tid; t < nt; t += 256) {
        const float xv = row[t];
        e_sh[t] = xv;
        lmax = fmaxf(lmax, xv);
    }
    red[tid] = lmax;
    __syncthreads();
    for (int off = 128; off > 0; off >>= 1) {
        if (tid < off) red[tid] = fmaxf(red[tid], red[tid + off]);
        __syncthreads();
    }
    const float mx = red[0];
    __syncthreads();

    float lsum = 0.f;
    for (int t = tid; t < nt; t += 256) {
        const float e = __expf(e_sh[t] - mx);
        e_sh[t] = e;
        lsum += e;
    }
    red[tid] = lsum;
    __syncthreads();
    for (int off = 128; off > 0; off >>= 1) {
        if (tid < off) red[tid] += red[tid + off];
        __syncthreads();
    }
    const float inv = 1.0f / red[0];
    __syncthreads();   // all row reads / e_sh writes done before overwrite

    const int tmax = ((s >> 7) + 1) << 7;   // round_up(s+1, 128)
    for (int t4 = tid * 4; t4 < tmax; t4 += 1024) {
        ushort4 o;
        o.x = (t4     < nt) ? f2bf(e_sh[t4    ] * inv) : (ushort_t)0;
        o.y = (t4 + 1 < nt) ? f2bf(e_sh[t4 + 1] * inv) : (ushort_t)0;
        o.z = (t4 + 2 < nt) ? f2bf(e_sh[t4 + 2] * inv) : (ushort_t)0;
        o.w = (t4 + 3 < nt) ? f2bf(e_sh[t4 + 3] * inv) : (ushort_t)0;
        *(ushort4*)(prow + t4) = o;
    }
}

// ---------------------------------------------------------------------------
// out = P @ V. P bf16 inside fp32 score buffer (lda = 2*SEQ ushorts).
// V^T (D x S) bf16; causal K-bound per row tile. fp32 out to d_out.
// ---------------------------------------------------------------------------
__global__ __launch_bounds__(256) void pv_gemm_mfma(
    const float* __restrict__ scoresP, const ushort_t* __restrict__ vt,
    float* __restrict__ outp)
{
    const int wg = xcd_swz(blockIdx.x, 8 * 16 * BATCH);
    const int b  = wg >> 7;
    const int r  = wg & 127;
    const int st = r >> 3;
    const int dt = r & 7;

    __shared__ __align__(16) ushort_t As[128 * 32];
    __shared__ __align__(16) ushort_t Bs[128 * 32];

    const ushort_t* A  = (const ushort_t*)(scoresP + (size_t)b * SEQ * SEQ);  // lda = 2*SEQ
    const ushort_t* Bt = vt + (size_t)b * DMODEL * SEQ;                        // ldb = SEQ
    float* out = outp + (size_t)b * SEQ * DMODEL;

    f32x4 acc[4][4];
    #pragma unroll
    for (int m = 0; m < 4; ++m)
        #pragma unroll
        for (int n = 0; n < 4; ++n)
            acc[m][n] = (f32x4)(0.f);

    const int ksteps = (st + 1) * 4;   // (s0+128)/32 K-steps of 32
    gemm_core_128(A, 2 * SEQ, Bt, SEQ, st * 128, dt * 128, ksteps, As, Bs, acc);

    const int l  = threadIdx.x & 63;
    const int w  = threadIdx.x >> 6;
    const int wr = w >> 1, wc = w & 1;
    #pragma unroll
    for (int m = 0; m < 4; ++m) {
        #pragma unroll
        for (int n = 0; n < 4; ++n) {
            const int gcol = dt * 128 + wc * 64 + n * 16 + (l & 15);
            #pragma unroll
            for (int j = 0; j < 4; ++j) {
                const int grow = st * 128 + wr * 64 + m * 16 + (l >> 4) * 4 + j;
                out[(size_t)grow * DMODEL + gcol] = acc[m][n][j];
            }
        }
    }
}

// ---------------------------------------------------------------------------
// Helpers: fp32 -> bf16 conversions / transposes
// ---------------------------------------------------------------------------
__global__ __launch_bounds__(256) void convert_bf16(
    const float* __restrict__ in, ushort_t* __restrict__ out, int n4)
{
    const int i = (blockIdx.x * 256 + threadIdx.x);
    if (i < n4) {
        const float4 f = *(const float4*)(in + (size_t)i * 4);
        ushort4 o;
        o.x = f2bf(f.x); o.y = f2bf(f.y); o.z = f2bf(f.z); o.w = f2bf(f.w);
        *(ushort4*)(out + (size_t)i * 4) = o;
    }
}

// W (K x N fp32) -> W^T (N x K bf16); z selects Wq/Wk/Wv
__global__ __launch_bounds__(256) void transpose_w(
    const float* __restrict__ Wq, const float* __restrict__ Wk, const float* __restrict__ Wv,
    ushort_t* __restrict__ wtq, ushort_t* __restrict__ wtk, ushort_t* __restrict__ wtv)
{
    const float* W; ushort_t* wt;
    const int z = blockIdx.z;
    if (z == 0)      { W = Wq; wt = wtq; }
    else if (z == 1) { W = Wk; wt = wtk; }
    else             { W = Wv; wt = wtv; }

    __shared__ float tile[32][33];
    const int k0 = blockIdx.x * 32, n0 = blockIdx.y * 32;
    const int x = threadIdx.x, y = threadIdx.y;
    #pragma unroll
    for (int i = 0; i < 4; ++i)
        tile[y + i * 8][x] = W[(size_t)(k0 + y + i * 8) * DMODEL + n0 + x];
    __syncthreads();
    #pragma unroll
    for (int i = 0; i < 4; ++i)
        wt[(size_t)(n0 + y + i * 8) * DMODEL + k0 + x] = f2bf(tile[x][y + i * 8]);
}

// V (B,S,D bf16) -> V^T (B,D,S bf16)
__global__ __launch_bounds__(256) void transpose_v(
    const ushort_t* __restrict__ v, ushort_t* __restrict__ vt)
{
    __shared__ ushort_t tile[32][33];
    const int b = blockIdx.z;
    const int t0 = blockIdx.x * 32, d0 = blockIdx.y * 32;
    const ushort_t* src = v + (size_t)b * SEQ * DMODEL;
    ushort_t* dst = vt + (size_t)b * DMODEL * SEQ;
    const int x = threadIdx.x, y = threadIdx.y;
    #pragma unroll
    for (int i = 0; i < 4; ++i)
        tile[y + i * 8][x] = src[(size_t)(t0 + y + i * 8) * DMODEL + d0 + x];
    __syncthreads();
    #pragma unroll
    for (int i = 0; i < 4; ++i)
        dst[(size_t)(d0 + y + i * 8) * SEQ + t0 + x] = tile[x][y + i * 8];
}

// ===========================================================================
// Fallback fp32 path
// ===========================================================================
__global__ __launch_bounds__(1024) void qkv_gemm_f32(
    const float* __restrict__ x,
    const float* __restrict__ Wq, const float* __restrict__ bq,
    const float* __restrict__ Wk, const float* __restrict__ bk,
    const float* __restrict__ Wv, const float* __restrict__ bv,
    float* __restrict__ q, float* __restrict__ k, float* __restrict__ v)
{
    const float* W; const float* bias; float* out;
    const int z = blockIdx.z;
    if (z == 0)      { W = Wq; bias = bq; out = q; }
    else if (z == 1) { W = Wk; bias = bk; out = k; }
    else             { W = Wv; bias = bv; out = v; }

    __shared__ float As[32][33];
    __shared__ float Bs[32][33];
    const int tx = threadIdx.x, ty = threadIdx.y;
    const int row = blockIdx.y * 32 + ty;
    const int col = blockIdx.x * 32 + tx;

    float acc = 0.f;
    for (int k0 = 0; k0 < DMODEL; k0 += 32) {
        As[ty][tx] = x[(size_t)row * DMODEL + k0 + tx];
        Bs[ty][tx] = W[(size_t)(k0 + ty) * DMODEL + col];
        __syncthreads();
        #pragma unroll
        for (int kk = 0; kk < 32; ++kk)
            acc += As[ty][kk] * Bs[kk][tx];
        __syncthreads();
    }
    out[(size_t)row * DMODEL + col] = acc + bias[col];
}

__global__ __launch_bounds__(256) void attn_f32(
    const float* __restrict__ q, const float* __restrict__ k,
    const float* __restrict__ v, float* __restrict__ out)
{
    const int s = blockIdx.x, b = blockIdx.y, tid = threadIdx.x;
    __shared__ float qs[DMODEL];
    __shared__ float sc[SEQ];
    __shared__ float red[256];
    const float* qrow = q + ((size_t)b * SEQ + s) * DMODEL;
    for (int d = tid; d < DMODEL; d += 256) qs[d] = qrow[d];
    __syncthreads();
    const float* kb = k + (size_t)b * SEQ * DMODEL;
    const int nt = s + 1;
    float lmax = -INFINITY;
    for (int t = tid; t < nt; t += 256) {
        const float* krow = kb + (size_t)t * DMODEL;
        float acc = 0.f;
        for (int d = 0; d < DMODEL; d += 4) {
            const float4 kv = *(const float4*)(krow + d);
            acc += qs[d] * kv.x + qs[d+1] * kv.y + qs[d+2] * kv.z + qs[d+3] * kv.w;
        }
        acc *= SCALE_INV; sc[t] = acc; lmax = fmaxf(lmax, acc);
    }
    red[tid] = lmax; __syncthreads();
    for (int off = 128; off > 0; off >>= 1) { if (tid < off) red[tid] = fmaxf(red[tid], red[tid+off]); __syncthreads(); }
    const float mx = red[0]; __syncthreads();
    float lsum = 0.f;
    for (int t = tid; t < nt; t += 256) { const float e = expf(sc[t]-mx); sc[t]=e; lsum+=e; }
    red[tid] = lsum; __syncthreads();
    for (int off = 128; off > 0; off >>= 1) { if (tid < off) red[tid] += red[tid+off]; __syncthreads(); }
    const float inv = 1.0f / red[0]; __syncthreads();
    const float* vb = v + (size_t)b * SEQ * DMODEL;
    float a0=0,a1=0,a2=0,a3=0;
    for (int t = 0; t < nt; ++t) {
        const float p = sc[t];
        const float* vrow = vb + (size_t)t * DMODEL;
        a0 += p*vrow[tid]; a1 += p*vrow[tid+256]; a2 += p*vrow[tid+512]; a3 += p*vrow[tid+768];
    }
    float* orow = out + ((size_t)b * SEQ + s) * DMODEL;
    orow[tid]=a0*inv; orow[tid+256]=a1*inv; orow[tid+512]=a2*inv; orow[tid+768]=a3*inv;
}

// ---------------------------------------------------------------------------
extern "C" void kernel_launch(void* const* d_in, const int* in_sizes, int n_in,
                              void* d_out, int out_size, void* d_ws, size_t ws_size,
                              hipStream_t stream)
{
    const float* x  = (const float*)d_in[0];
    // d_in[1] = mask (int32 tril) — causal structure hardcoded
    const float* Wq = (const float*)d_in[2];
    const float* bq = (const float*)d_in[3];
    const float* Wk = (const float*)d_in[4];
    const float* bk = (const float*)d_in[5];
    const float* Wv = (const float*)d_in[6];
    const float* bv = (const float*)d_in[7];
    float* out = (float*)d_out;

    const size_t SZ_XBF   = (size_t)BATCH * SEQ * DMODEL * 2;      // 16 MB
    const size_t SZ_WT    = (size_t)DMODEL * DMODEL * 2;           // 2 MB each
    const size_t SZ_QKV   = (size_t)BATCH * SEQ * DMODEL * 2;      // 16 MB each
    const size_t SZ_VT    = (size_t)BATCH * DMODEL * SEQ * 2;      // 16 MB
    const size_t SZ_SC    = (size_t)BATCH * SEQ * SEQ * 4;         // 67 MB
    const size_t NEED = SZ_XBF + 3 * SZ_WT + 3 * SZ_QKV + SZ_VT + SZ_SC;  // ~150 MB

    if (ws_size >= NEED) {
        char* p = (char*)d_ws;
        ushort_t* x_bf = (ushort_t*)p;              p += SZ_XBF;
        ushort_t* wtq  = (ushort_t*)p;              p += SZ_WT;
        ushort_t* wtk  = (ushort_t*)p;              p += SZ_WT;
        ushort_t* wtv  = (ushort_t*)p;              p += SZ_WT;
        ushort_t* q_bf = (ushort_t*)p;              p += SZ_QKV;
        ushort_t* k_bf = (ushort_t*)p;              p += SZ_QKV;
        ushort_t* v_bf = (ushort_t*)p;              p += SZ_QKV;
        ushort_t* vt   = (ushort_t*)p;              p += SZ_VT;
        float*    sc   = (float*)p;

        const int n4 = BATCH * SEQ * DMODEL / 4;
        hipLaunchKernelGGL(convert_bf16, dim3((n4 + 255) / 256), dim3(256), 0, stream,
                           x, x_bf, n4);
        hipLaunchKernelGGL(transpose_w, dim3(32, 32, 3), dim3(32, 8), 0, stream,
                           Wq, Wk, Wv, wtq, wtk, wtv);
        hipLaunchKernelGGL(qkv_gemm_mfma, dim3(8 * 64 * 3), dim3(256), 0, stream,
                           x_bf, wtq, wtk, wtv, bq, bk, bv, q_bf, k_bf, v_bf);
        hipLaunchKernelGGL(transpose_v, dim3(SEQ / 32, DMODEL / 32, BATCH), dim3(32, 8), 0, stream,
                           v_bf, vt);
        hipLaunchKernelGGL(qkt_gemm_mfma, dim3(16 * 16 * BATCH), dim3(256), 0, stream,
                           q_bf, k_bf, sc);
        hipLaunchKernelGGL(softmax_rows, dim3(SEQ, BATCH), dim3(256), 0, stream, sc);
        hipLaunchKernelGGL(pv_gemm_mfma, dim3(8 * 16 * BATCH), dim3(256), 0, stream,
                           sc, vt, out);
    } else {
        const size_t elems = (size_t)BATCH * SEQ * DMODEL;
        float* q = (float*)d_ws;
        float* k = q + elems;
        float* v = k + elems;
        hipLaunchKernelGGL(qkv_gemm_f32, dim3(DMODEL / 32, BATCH * SEQ / 32, 3), dim3(32, 32), 0, stream,
                           x, Wq, bq, Wk, bk, Wv, bv, q, k, v);
        hipLaunchKernelGGL(attn_f32, dim3(SEQ, BATCH), dim3(256), 0, stream, q, k, v, out);
    }
}

// Round 4
// 206.741 us; speedup vs baseline: 1.2885x; 1.2885x over previous
//
#include <hip/hip_runtime.h>
#include <math.h>

#define DMODEL 1024
#define SEQ 2048
#define BATCH 4
#define SCALE_INV (1.0f/32.0f)   // 1/sqrt(1024)

typedef unsigned short ushort_t;
typedef __attribute__((ext_vector_type(8))) short bf16x8;   // 8 bf16 in 4 VGPRs
typedef __attribute__((ext_vector_type(4))) float f32x4;

// fp32 -> bf16, round-to-nearest-even
__device__ __forceinline__ ushort_t f2bf(float f) {
    unsigned int u = __float_as_uint(f);
    unsigned int rounding = 0x7FFFu + ((u >> 16) & 1u);
    return (ushort_t)((u + rounding) >> 16);
}

#define GLOAD16(SRC, DST) \
    __builtin_amdgcn_global_load_lds( \
        (const __attribute__((address_space(1))) void*)(SRC), \
        (__attribute__((address_space(3))) void*)(DST), 16, 0, 0)

// bijective XCD swizzle (nwg % 8 == 0)
__device__ __forceinline__ int xcd_swz(int bid, int nwg) {
    return (bid & 7) * (nwg >> 3) + (bid >> 3);
}

// ---------------------------------------------------------------------------
// Shared MFMA GEMM core: C(128x128) += A(128xK) * Bt(128xK)^T
// A row-major MxK (lda), Bt row-major NxK (ldb), both K-contiguous.
// 256 threads = 4 waves (2x2); each wave owns 64x64 = 4x4 16x16x32 fragments.
//
// LDS: linear row-major [128][32] per operand, staged with contiguous-lane
// global_load_lds (lane quads read one 64B row segment -> full coalescing).
// Bank-conflict mitigation: 16B k-slot XOR within each 64B row,
//   LDS[row, kg] = G[row, kg ^ (row&3)]
// applied identically on the staging SOURCE and the fragment READ (the same
// involution both sides, rule #21). Fragment ds_read_b128: 4-way on 4 banks
// (was 8-way on 2). Staging coalescing unchanged vs the known-good pattern.
// ---------------------------------------------------------------------------
__device__ __forceinline__ void gemm_core_128(
    const ushort_t* __restrict__ A, int lda,
    const ushort_t* __restrict__ Bt, int ldb,
    int arow0, int brow0, int ksteps,
    ushort_t* As, ushort_t* Bs,
    f32x4 acc[4][4])
{
    const int tid = threadIdx.x;
    const int l   = tid & 63;
    const int w   = tid >> 6;      // wave 0..3
    const int wr  = w >> 1;        // wave row (0..1)
    const int wc  = w & 1;         // wave col (0..1)
    // staging: lane reads row = off>>6, k-slot (l&3) ^ (row&3); row&3 == (l>>2)&3
    const int ke_swz = (((l & 3) ^ ((l >> 2) & 3)) * 8);
    // fragment read: row&3 == l&3, so k-slot = (l>>4) ^ (l&3)
    const int kgx = (l >> 4) ^ (l & 3);

    for (int s = 0; s < ksteps; ++s) {
        const int k0 = s * 32;
        #pragma unroll
        for (int i = 0; i < 2; ++i) {
            const int off = i * 4096 + w * 1024 + l * 16;   // byte offset in As
            const int row = off >> 6;                        // 64 B per row
            GLOAD16(A + (size_t)(arow0 + row) * lda + k0 + ke_swz,
                    (char*)As + i * 4096 + w * 1024);
        }
        #pragma unroll
        for (int i = 0; i < 2; ++i) {
            const int off = i * 4096 + w * 1024 + l * 16;
            const int row = off >> 6;
            GLOAD16(Bt + (size_t)(brow0 + row) * ldb + k0 + ke_swz,
                    (char*)Bs + i * 4096 + w * 1024);
        }
        __syncthreads();   // drains vmcnt(0) then barrier

        bf16x8 a[4], b[4];
        #pragma unroll
        for (int m = 0; m < 4; ++m)
            a[m] = *(const bf16x8*)(As + (wr * 64 + m * 16 + (l & 15)) * 32 + kgx * 8);
        #pragma unroll
        for (int n = 0; n < 4; ++n)
            b[n] = *(const bf16x8*)(Bs + (wc * 64 + n * 16 + (l & 15)) * 32 + kgx * 8);
        #pragma unroll
        for (int m = 0; m < 4; ++m)
            #pragma unroll
            for (int n = 0; n < 4; ++n)
                acc[m][n] = __builtin_amdgcn_mfma_f32_16x16x32_bf16(a[m], b[n], acc[m][n], 0, 0, 0);
        __syncthreads();   // protect LDS before next staging
    }
}

// ---------------------------------------------------------------------------
// QKV projection: out = x @ W + b  (W^T pre-transposed to N x K bf16).
// z = Q (scaled) / K / V. V is written TRANSPOSED (B, D, S) directly ->
// no separate transpose_v kernel.
// ---------------------------------------------------------------------------
__global__ __launch_bounds__(256) void qkv_gemm_mfma(
    const ushort_t* __restrict__ x,
    const ushort_t* __restrict__ wtq, const ushort_t* __restrict__ wtk, const ushort_t* __restrict__ wtv,
    const float* __restrict__ bq, const float* __restrict__ bk, const float* __restrict__ bv,
    ushort_t* __restrict__ q, ushort_t* __restrict__ k, ushort_t* __restrict__ vt)
{
    __shared__ __align__(16) ushort_t As[128 * 32];
    __shared__ __align__(16) ushort_t Bs[128 * 32];

    const int wg = xcd_swz(blockIdx.x, 8 * 64 * 3);
    const int z  = wg >> 9;           // 512 blocks per matrix
    const int r  = wg & 511;
    const int by = r >> 3;            // row tile (64)
    const int bx = r & 7;             // col tile (8) fastest: shares A-panel

    const ushort_t* Bt; const float* bias; float scale;
    if (z == 0)      { Bt = wtq; bias = bq; scale = SCALE_INV; }
    else if (z == 1) { Bt = wtk; bias = bk; scale = 1.0f; }
    else             { Bt = wtv; bias = bv; scale = 1.0f; }

    const int arow0 = by * 128;
    const int brow0 = bx * 128;

    f32x4 acc[4][4];
    #pragma unroll
    for (int m = 0; m < 4; ++m)
        #pragma unroll
        for (int n = 0; n < 4; ++n)
            acc[m][n] = (f32x4)(0.f);

    gemm_core_128(x, DMODEL, Bt, DMODEL, arow0, brow0, DMODEL / 32, As, Bs, acc);

    const int l  = threadIdx.x & 63;
    const int w  = threadIdx.x >> 6;
    const int wr = w >> 1, wc = w & 1;

    if (z < 2) {
        ushort_t* out = (z == 0) ? q : k;
        #pragma unroll
        for (int n = 0; n < 4; ++n) {
            const int gcol = brow0 + wc * 64 + n * 16 + (l & 15);
            const float bb = bias[gcol];
            #pragma unroll
            for (int m = 0; m < 4; ++m) {
                #pragma unroll
                for (int j = 0; j < 4; ++j) {
                    const int grow = arow0 + wr * 64 + m * 16 + (l >> 4) * 4 + j;
                    out[(size_t)grow * DMODEL + gcol] = f2bf((acc[m][n][j] + bb) * scale);
                }
            }
        }
    } else {
        // V: write transposed (B, D, S). Row tile never crosses a batch
        // boundary (2048 % 128 == 0); b is block-uniform.
        ushort_t* vtb = vt + (size_t)(arow0 >> 11) * DMODEL * SEQ;
        #pragma unroll
        for (int n = 0; n < 4; ++n) {
            const int gcol = brow0 + wc * 64 + n * 16 + (l & 15);   // d index
            const float bb = bias[gcol];
            #pragma unroll
            for (int m = 0; m < 4; ++m) {
                const int t0 = (arow0 & 2047) + wr * 64 + m * 16 + (l >> 4) * 4;
                ushort4 o;
                o.x = f2bf(acc[m][n][0] + bb);
                o.y = f2bf(acc[m][n][1] + bb);
                o.z = f2bf(acc[m][n][2] + bb);
                o.w = f2bf(acc[m][n][3] + bb);
                *(ushort4*)(vtb + (size_t)gcol * SEQ + t0) = o;   // 8B contiguous
            }
        }
    }
}

// ---------------------------------------------------------------------------
// scores = Q K^T (scale folded into Q). Triangular block skip. fp32 out.
// ---------------------------------------------------------------------------
__global__ __launch_bounds__(256) void qkt_gemm_mfma(
    const ushort_t* __restrict__ q, const ushort_t* __restrict__ k,
    float* __restrict__ scores)
{
    const int wg = xcd_swz(blockIdx.x, 16 * 16 * BATCH);
    const int b  = wg >> 8;
    const int r  = wg & 255;
    const int st = r >> 4;
    const int tt = r & 15;
    if (tt > st) return;         // fully masked block

    __shared__ __align__(16) ushort_t As[128 * 32];
    __shared__ __align__(16) ushort_t Bs[128 * 32];

    const ushort_t* A  = q + (size_t)b * SEQ * DMODEL;
    const ushort_t* Bt = k + (size_t)b * SEQ * DMODEL;
    float* out = scores + (size_t)b * SEQ * SEQ;

    f32x4 acc[4][4];
    #pragma unroll
    for (int m = 0; m < 4; ++m)
        #pragma unroll
        for (int n = 0; n < 4; ++n)
            acc[m][n] = (f32x4)(0.f);

    gemm_core_128(A, DMODEL, Bt, DMODEL, st * 128, tt * 128, DMODEL / 32, As, Bs, acc);

    const int l  = threadIdx.x & 63;
    const int w  = threadIdx.x >> 6;
    const int wr = w >> 1, wc = w & 1;
    #pragma unroll
    for (int m = 0; m < 4; ++m) {
        #pragma unroll
        for (int n = 0; n < 4; ++n) {
            const int gcol = tt * 128 + wc * 64 + n * 16 + (l & 15);
            #pragma unroll
            for (int j = 0; j < 4; ++j) {
                const int grow = st * 128 + wr * 64 + m * 16 + (l >> 4) * 4 + j;
                out[(size_t)grow * SEQ + gcol] = acc[m][n][j];
            }
        }
    }
}

// ---------------------------------------------------------------------------
// Row softmax over causal prefix; writes P (bf16) in place over the fp32 row.
// ---------------------------------------------------------------------------
__global__ __launch_bounds__(256) void softmax_rows(float* __restrict__ scores)
{
    const int s = blockIdx.x;
    const int b = blockIdx.y;
    const int tid = threadIdx.x;

    float* row = scores + ((size_t)b * SEQ + s) * SEQ;
    ushort_t* prow = (ushort_t*)row;
    const int nt = s + 1;

    __shared__ float e_sh[SEQ];    // 8 KB
    __shared__ float red[256];

    float lmax = -INFINITY;
    const int nt4 = nt >> 2;
    for (int i = tid; i < nt4; i += 256) {
        const float4 f = ((const float4*)row)[i];
        ((float4*)e_sh)[i] = f;
        lmax = fmaxf(lmax, fmaxf(fmaxf(f.x, f.y), fmaxf(f.z, f.w)));
    }
    for (int t = nt4 * 4 + tid; t < nt; t += 256) {
        const float xv = row[t];
        e_sh[t] = xv;
        lmax = fmaxf(lmax, xv);
    }
    red[tid] = lmax;
    __syncthreads();
    for (int off = 128; off > 0; off >>= 1) {
        if (tid < off) red[tid] = fmaxf(red[tid], red[tid + off]);
        __syncthreads();
    }
    const float mx = red[0];
    __syncthreads();

    float lsum = 0.f;
    for (int t = tid; t < nt; t += 256) {
        const float e = __expf(e_sh[t] - mx);
        e_sh[t] = e;
        lsum += e;
    }
    red[tid] = lsum;
    __syncthreads();
    for (int off = 128; off > 0; off >>= 1) {
        if (tid < off) red[tid] += red[tid + off];
        __syncthreads();
    }
    const float inv = 1.0f / red[0];
    __syncthreads();   // all row reads / e_sh writes done before overwrite

    const int tmax = ((s >> 7) + 1) << 7;   // round_up(s+1, 128)
    for (int t4 = tid * 4; t4 < tmax; t4 += 1024) {
        ushort4 o;
        o.x = (t4     < nt) ? f2bf(e_sh[t4    ] * inv) : (ushort_t)0;
        o.y = (t4 + 1 < nt) ? f2bf(e_sh[t4 + 1] * inv) : (ushort_t)0;
        o.z = (t4 + 2 < nt) ? f2bf(e_sh[t4 + 2] * inv) : (ushort_t)0;
        o.w = (t4 + 3 < nt) ? f2bf(e_sh[t4 + 3] * inv) : (ushort_t)0;
        *(ushort4*)(prow + t4) = o;
    }
}

// ---------------------------------------------------------------------------
// out = P @ V. P bf16 inside fp32 score buffer (lda = 2*SEQ ushorts).
// V^T (D x S) bf16; causal K-bound per row tile. fp32 out to d_out.
// ---------------------------------------------------------------------------
__global__ __launch_bounds__(256) void pv_gemm_mfma(
    const float* __restrict__ scoresP, const ushort_t* __restrict__ vt,
    float* __restrict__ outp)
{
    const int wg = xcd_swz(blockIdx.x, 8 * 16 * BATCH);
    const int b  = wg >> 7;
    const int r  = wg & 127;
    const int st = r >> 3;
    const int dt = r & 7;

    __shared__ __align__(16) ushort_t As[128 * 32];
    __shared__ __align__(16) ushort_t Bs[128 * 32];

    const ushort_t* A  = (const ushort_t*)(scoresP + (size_t)b * SEQ * SEQ);  // lda = 2*SEQ
    const ushort_t* Bt = vt + (size_t)b * DMODEL * SEQ;                        // ldb = SEQ
    float* out = outp + (size_t)b * SEQ * DMODEL;

    f32x4 acc[4][4];
    #pragma unroll
    for (int m = 0; m < 4; ++m)
        #pragma unroll
        for (int n = 0; n < 4; ++n)
            acc[m][n] = (f32x4)(0.f);

    const int ksteps = (st + 1) * 4;   // (s0+128)/32 K-steps of 32
    gemm_core_128(A, 2 * SEQ, Bt, SEQ, st * 128, dt * 128, ksteps, As, Bs, acc);

    const int l  = threadIdx.x & 63;
    const int w  = threadIdx.x >> 6;
    const int wr = w >> 1, wc = w & 1;
    #pragma unroll
    for (int m = 0; m < 4; ++m) {
        #pragma unroll
        for (int n = 0; n < 4; ++n) {
            const int gcol = dt * 128 + wc * 64 + n * 16 + (l & 15);
            #pragma unroll
            for (int j = 0; j < 4; ++j) {
                const int grow = st * 128 + wr * 64 + m * 16 + (l >> 4) * 4 + j;
                out[(size_t)grow * DMODEL + gcol] = acc[m][n][j];
            }
        }
    }
}

// ---------------------------------------------------------------------------
// Helpers
// ---------------------------------------------------------------------------
__global__ __launch_bounds__(256) void convert_bf16(
    const float* __restrict__ in, ushort_t* __restrict__ out, int n4)
{
    const int i = (blockIdx.x * 256 + threadIdx.x);
    if (i < n4) {
        const float4 f = *(const float4*)(in + (size_t)i * 4);
        ushort4 o;
        o.x = f2bf(f.x); o.y = f2bf(f.y); o.z = f2bf(f.z); o.w = f2bf(f.w);
        *(ushort4*)(out + (size_t)i * 4) = o;
    }
}

// W (K x N fp32) -> W^T (N x K bf16); z selects Wq/Wk/Wv
__global__ __launch_bounds__(256) void transpose_w(
    const float* __restrict__ Wq, const float* __restrict__ Wk, const float* __restrict__ Wv,
    ushort_t* __restrict__ wtq, ushort_t* __restrict__ wtk, ushort_t* __restrict__ wtv)
{
    const float* W; ushort_t* wt;
    const int z = blockIdx.z;
    if (z == 0)      { W = Wq; wt = wtq; }
    else if (z == 1) { W = Wk; wt = wtk; }
    else             { W = Wv; wt = wtv; }

    __shared__ float tile[32][33];
    const int k0 = blockIdx.x * 32, n0 = blockIdx.y * 32;
    const int x = threadIdx.x, y = threadIdx.y;
    #pragma unroll
    for (int i = 0; i < 4; ++i)
        tile[y + i * 8][x] = W[(size_t)(k0 + y + i * 8) * DMODEL + n0 + x];
    __syncthreads();
    #pragma unroll
    for (int i = 0; i < 4; ++i)
        wt[(size_t)(n0 + y + i * 8) * DMODEL + k0 + x] = f2bf(tile[x][y + i * 8]);
}

// ===========================================================================
// Fallback fp32 path
// ===========================================================================
__global__ __launch_bounds__(1024) void qkv_gemm_f32(
    const float* __restrict__ x,
    const float* __restrict__ Wq, const float* __restrict__ bq,
    const float* __restrict__ Wk, const float* __restrict__ bk,
    const float* __restrict__ Wv, const float* __restrict__ bv,
    float* __restrict__ q, float* __restrict__ k, float* __restrict__ v)
{
    const float* W; const float* bias; float* out;
    const int z = blockIdx.z;
    if (z == 0)      { W = Wq; bias = bq; out = q; }
    else if (z == 1) { W = Wk; bias = bk; out = k; }
    else             { W = Wv; bias = bv; out = v; }

    __shared__ float As[32][33];
    __shared__ float Bs[32][33];
    const int tx = threadIdx.x, ty = threadIdx.y;
    const int row = blockIdx.y * 32 + ty;
    const int col = blockIdx.x * 32 + tx;

    float acc = 0.f;
    for (int k0 = 0; k0 < DMODEL; k0 += 32) {
        As[ty][tx] = x[(size_t)row * DMODEL + k0 + tx];
        Bs[ty][tx] = W[(size_t)(k0 + ty) * DMODEL + col];
        __syncthreads();
        #pragma unroll
        for (int kk = 0; kk < 32; ++kk)
            acc += As[ty][kk] * Bs[kk][tx];
        __syncthreads();
    }
    out[(size_t)row * DMODEL + col] = acc + bias[col];
}

__global__ __launch_bounds__(256) void attn_f32(
    const float* __restrict__ q, const float* __restrict__ k,
    const float* __restrict__ v, float* __restrict__ out)
{
    const int s = blockIdx.x, b = blockIdx.y, tid = threadIdx.x;
    __shared__ float qs[DMODEL];
    __shared__ float sc[SEQ];
    __shared__ float red[256];
    const float* qrow = q + ((size_t)b * SEQ + s) * DMODEL;
    for (int d = tid; d < DMODEL; d += 256) qs[d] = qrow[d];
    __syncthreads();
    const float* kb = k + (size_t)b * SEQ * DMODEL;
    const int nt = s + 1;
    float lmax = -INFINITY;
    for (int t = tid; t < nt; t += 256) {
        const float* krow = kb + (size_t)t * DMODEL;
        float acc = 0.f;
        for (int d = 0; d < DMODEL; d += 4) {
            const float4 kv = *(const float4*)(krow + d);
            acc += qs[d] * kv.x + qs[d+1] * kv.y + qs[d+2] * kv.z + qs[d+3] * kv.w;
        }
        acc *= SCALE_INV; sc[t] = acc; lmax = fmaxf(lmax, acc);
    }
    red[tid] = lmax; __syncthreads();
    for (int off = 128; off > 0; off >>= 1) { if (tid < off) red[tid] = fmaxf(red[tid], red[tid+off]); __syncthreads(); }
    const float mx = red[0]; __syncthreads();
    float lsum = 0.f;
    for (int t = tid; t < nt; t += 256) { const float e = expf(sc[t]-mx); sc[t]=e; lsum+=e; }
    red[tid] = lsum; __syncthreads();
    for (int off = 128; off > 0; off >>= 1) { if (tid < off) red[tid] += red[tid+off]; __syncthreads(); }
    const float inv = 1.0f / red[0]; __syncthreads();
    const float* vb = v + (size_t)b * SEQ * DMODEL;
    float a0=0,a1=0,a2=0,a3=0;
    for (int t = 0; t < nt; ++t) {
        const float p = sc[t];
        const float* vrow = vb + (size_t)t * DMODEL;
        a0 += p*vrow[tid]; a1 += p*vrow[tid+256]; a2 += p*vrow[tid+512]; a3 += p*vrow[tid+768];
    }
    float* orow = out + ((size_t)b * SEQ + s) * DMODEL;
    orow[tid]=a0*inv; orow[tid+256]=a1*inv; orow[tid+512]=a2*inv; orow[tid+768]=a3*inv;
}

// ---------------------------------------------------------------------------
extern "C" void kernel_launch(void* const* d_in, const int* in_sizes, int n_in,
                              void* d_out, int out_size, void* d_ws, size_t ws_size,
                              hipStream_t stream)
{
    const float* x  = (const float*)d_in[0];
    // d_in[1] = mask (int32 tril) — causal structure hardcoded
    const float* Wq = (const float*)d_in[2];
    const float* bq = (const float*)d_in[3];
    const float* Wk = (const float*)d_in[4];
    const float* bk = (const float*)d_in[5];
    const float* Wv = (const float*)d_in[6];
    const float* bv = (const float*)d_in[7];
    float* out = (float*)d_out;

    const size_t SZ_XBF   = (size_t)BATCH * SEQ * DMODEL * 2;      // 16 MB
    const size_t SZ_WT    = (size_t)DMODEL * DMODEL * 2;           // 2 MB each
    const size_t SZ_QKV   = (size_t)BATCH * SEQ * DMODEL * 2;      // 16 MB each
    const size_t SZ_SC    = (size_t)BATCH * SEQ * SEQ * 4;         // 67 MB
    const size_t NEED = SZ_XBF + 3 * SZ_WT + 3 * SZ_QKV + SZ_SC;   // ~137 MB

    if (ws_size >= NEED) {
        char* p = (char*)d_ws;
        ushort_t* x_bf = (ushort_t*)p;              p += SZ_XBF;
        ushort_t* wtq  = (ushort_t*)p;              p += SZ_WT;
        ushort_t* wtk  = (ushort_t*)p;              p += SZ_WT;
        ushort_t* wtv  = (ushort_t*)p;              p += SZ_WT;
        ushort_t* q_bf = (ushort_t*)p;              p += SZ_QKV;
        ushort_t* k_bf = (ushort_t*)p;              p += SZ_QKV;
        ushort_t* vt   = (ushort_t*)p;              p += SZ_QKV;   // V^T (B,D,S)
        float*    sc   = (float*)p;

        const int n4 = BATCH * SEQ * DMODEL / 4;
        hipLaunchKernelGGL(convert_bf16, dim3((n4 + 255) / 256), dim3(256), 0, stream,
                           x, x_bf, n4);
        hipLaunchKernelGGL(transpose_w, dim3(32, 32, 3), dim3(32, 8), 0, stream,
                           Wq, Wk, Wv, wtq, wtk, wtv);
        hipLaunchKernelGGL(qkv_gemm_mfma, dim3(8 * 64 * 3), dim3(256), 0, stream,
                           x_bf, wtq, wtk, wtv, bq, bk, bv, q_bf, k_bf, vt);
        hipLaunchKernelGGL(qkt_gemm_mfma, dim3(16 * 16 * BATCH), dim3(256), 0, stream,
                           q_bf, k_bf, sc);
        hipLaunchKernelGGL(softmax_rows, dim3(SEQ, BATCH), dim3(256), 0, stream, sc);
        hipLaunchKernelGGL(pv_gemm_mfma, dim3(8 * 16 * BATCH), dim3(256), 0, stream,
                           sc, vt, out);
    } else {
        const size_t elems = (size_t)BATCH * SEQ * DMODEL;
        float* q = (float*)d_ws;
        float* k = q + elems;
        float* v = k + elems;
        hipLaunchKernelGGL(qkv_gemm_f32, dim3(DMODEL / 32, BATCH * SEQ / 32, 3), dim3(32, 32), 0, stream,
                           x, Wq, bq, Wk, bk, Wv, bv, q, k, v);
        hipLaunchKernelGGL(attn_f32, dim3(SEQ, BATCH), dim3(256), 0, stream, q, k, v, out);
    }
}